// Round 6
// baseline (865.234 us; speedup 1.0000x reference)
//
#include <hip/hip_runtime.h>
#include <hip/hip_fp16.h>
#include <hip/hip_cooperative_groups.h>

namespace cg = cooperative_groups;

#define N_NODES 50000
#define N_EDGES 600000
#define N_GRAPHS 64
#define IN_D 5
#define HID 128
#define EMB 64

#define GRID 256
#define BLOCK 256
#define NTHREADS (GRID * BLOCK)       // 65536
#define NWAVES (NTHREADS / 64)        // 1024
#define CHUNK 512
#define NCHUNK ((N_NODES + CHUNK - 1) / CHUNK)   // 98

typedef _Float16 half8 __attribute__((ext_vector_type(8)));
typedef float float4v __attribute__((ext_vector_type(4)));

struct Params {
    const float* x; const int* src; const int* dst; const int* batch;
    const float* W1; const float* b1; const float* W2; const float* b2;
    const float* W3; const float* b3;
    const float* g1; const float* be1; const float* g2; const float* be2;
    const float* g3; const float* be3;
    const float* Wp; const float* bp;
    float* out;
    int* cnt; int* fill; int* row_start; int* csum; float* dinv;
    int2* e_pack; _Float16* Wt2; _Float16* Wt3;
    __half2* H16; __half2* A16; float* bufA;
    float* psum; float* pcnt;
};

// ---- shared device helpers ----

template <int STRIDE_W>
__device__ __forceinline__ void agg_body(const __half2* __restrict__ H2,
        const float* __restrict__ dinv, const int* __restrict__ row_start,
        const int2* __restrict__ e_pack, __half2* __restrict__ A16,
        int gw, int lane) {
    for (int n = gw; n < N_NODES; n += STRIDE_W) {
        float2 acc = make_float2(0.f, 0.f);
        int beg = row_start[n], end = row_start[n + 1];
        int e = beg;
        for (; e + 7 < end; e += 8) {
            int2 p[8];
            float2 h[8];
            #pragma unroll
            for (int u = 0; u < 8; ++u) p[u] = e_pack[e + u];
            #pragma unroll
            for (int u = 0; u < 8; ++u)
                h[u] = __half22float2(H2[(size_t)p[u].x * 64 + lane]);
            #pragma unroll
            for (int u = 0; u < 8; ++u) {
                float w = __int_as_float(p[u].y);
                acc.x = fmaf(w, h[u].x, acc.x);
                acc.y = fmaf(w, h[u].y, acc.y);
            }
        }
        for (; e + 3 < end; e += 4) {
            int2 p[4];
            float2 h[4];
            #pragma unroll
            for (int u = 0; u < 4; ++u) p[u] = e_pack[e + u];
            #pragma unroll
            for (int u = 0; u < 4; ++u)
                h[u] = __half22float2(H2[(size_t)p[u].x * 64 + lane]);
            #pragma unroll
            for (int u = 0; u < 4; ++u) {
                float w = __int_as_float(p[u].y);
                acc.x = fmaf(w, h[u].x, acc.x);
                acc.y = fmaf(w, h[u].y, acc.y);
            }
        }
        for (; e < end; ++e) {
            int2 pe = e_pack[e];
            float w = __int_as_float(pe.y);
            float2 f = __half22float2(H2[(size_t)pe.x * 64 + lane]);
            acc.x = fmaf(w, f.x, acc.x);
            acc.y = fmaf(w, f.y, acc.y);
        }
        float di = dinv[n];
        float2 hs = __half22float2(H2[(size_t)n * 64 + lane]);
        acc.x = fmaf(di, hs.x, acc.x);
        acc.y = fmaf(di, hs.y, acc.y);
        A16[(size_t)n * 64 + lane] = __floats2half2_rn(di * acc.x, di * acc.y);
    }
}

// MFMA fp16 GEMM tile: wave w of the block handles rows [tile*64+w*16,+16).
// A[m=lane&15][k=quad*8+j]; B via f-major Wt; C/D col=lane&15,row=quad*4+reg.
template <int STRIDE_B>
__device__ __forceinline__ void gemm_body(const _Float16* __restrict__ A16,
        const _Float16* __restrict__ Wt, const float* __restrict__ bb,
        const float* __restrict__ gg, const float* __restrict__ bee,
        float* __restrict__ outF, _Float16* __restrict__ outH,
        int blk, int t, float rs) {
    int w = t >> 6, lane = t & 63;
    int quad = lane >> 4, r16 = lane & 15;
    for (int tile = blk; tile * 64 < N_NODES; tile += STRIDE_B) {
        int nb = tile * 64 + w * 16;
        const half8* Arow = (const half8*)(A16 + (size_t)(nb + r16) * 128);
        half8 a[4];
        #pragma unroll
        for (int kb = 0; kb < 4; ++kb) a[kb] = Arow[kb * 4 + quad];
        #pragma unroll
        for (int ft = 0; ft < 8; ++ft) {
            int f = ft * 16 + r16;
            const half8* Brow = (const half8*)(Wt + (size_t)f * 128);
            float4v acc = {0.f, 0.f, 0.f, 0.f};
            #pragma unroll
            for (int kb = 0; kb < 4; ++kb)
                acc = __builtin_amdgcn_mfma_f32_16x16x32_f16(a[kb], Brow[kb * 4 + quad],
                                                             acc, 0, 0, 0);
            float b0 = bb[f], g0 = gg[f] * rs, e0 = bee[f];
            #pragma unroll
            for (int rr = 0; rr < 4; ++rr) {
                int n = nb + quad * 4 + rr;
                if (n < N_NODES) {
                    float v = fmaf(acc[rr] + b0, g0, e0);
                    v = v > 0.f ? v : 0.f;
                    if (outH) outH[(size_t)n * 128 + f] = (_Float16)v;
                    else      outF[(size_t)n * 128 + f] = v;
                }
            }
        }
    }
}

// ---- the cooperative mega kernel ----

__global__ __launch_bounds__(BLOCK, 2) void k_mega(Params p) {
    cg::grid_group grid = cg::this_grid();
    const int t = threadIdx.x;
    const int b = blockIdx.x;
    const int tid = b * BLOCK + t;
    const int lane = t & 63;
    const int gw = tid >> 6;
    const float rs = rsqrtf(1.0f + 1e-5f);
    __shared__ int sh[256];
    __shared__ int ws[8];

    // P0: zero counters/accumulators, fp16-transpose W2/W3
    for (int i = tid; i < N_NODES; i += NTHREADS) { p.cnt[i] = 0; p.fill[i] = 0; }
    for (int i = tid; i < N_GRAPHS * HID; i += NTHREADS) p.psum[i] = 0.f;
    if (tid < N_GRAPHS) p.pcnt[tid] = 0.f;
    if (tid == 0) p.row_start[N_NODES] = N_EDGES;
    for (int i = tid; i < 2 * HID * HID; i += NTHREADS) {
        int rem = i & (HID * HID - 1);
        int k = rem & 127, f = rem >> 7;
        if (i < HID * HID) p.Wt2[rem] = (_Float16)p.W2[k * HID + f];
        else               p.Wt3[rem] = (_Float16)p.W3[k * HID + f];
    }
    grid.sync();

    // P1: degree count
    for (int e = tid; e < N_EDGES; e += NTHREADS) atomicAdd(&p.cnt[p.dst[e]], 1);
    grid.sync();

    // P2: per-chunk sums + dinv
    if (b < NCHUNK) {
        int i0 = b * CHUNK + t, i1 = i0 + 256;
        int v = 0;
        if (i0 < N_NODES) { int c = p.cnt[i0]; v += c; p.dinv[i0] = rsqrtf((float)c + 1.0f); }
        if (i1 < N_NODES) { int c = p.cnt[i1]; v += c; p.dinv[i1] = rsqrtf((float)c + 1.0f); }
        sh[t] = v; __syncthreads();
        for (int off = 128; off > 0; off >>= 1) {
            if (t < off) sh[t] += sh[t + off];
            __syncthreads();
        }
        if (t == 0) p.csum[b] = sh[0];
    }
    grid.sync();

    // P4: per-chunk exclusive scan -> row_start. Each block redundantly
    // wave-reduces csum[0..b-1] for its chunk offset (folds old P3 + a sync).
    if (b < NCHUNK) {
        int pre = 0;
        for (int j = lane; j < b; j += 64) pre += p.csum[j];
        #pragma unroll
        for (int off = 32; off > 0; off >>= 1) pre += __shfl_down(pre, off);
        pre = __shfl(pre, 0);

        int base = b * CHUNK;
        int i0 = base + 2 * t, i1 = i0 + 1;
        int c0 = (i0 < N_NODES) ? p.cnt[i0] : 0;
        int c1 = (i1 < N_NODES) ? p.cnt[i1] : 0;
        int v = c0 + c1;
        int w = t >> 6;
        int s = v;
        #pragma unroll
        for (int off = 1; off < 64; off <<= 1) {
            int u = __shfl_up(s, off);
            if (lane >= off) s += u;
        }
        if (lane == 63) ws[w] = s;
        __syncthreads();
        if (t == 0) {
            int r = 0;
            #pragma unroll
            for (int j = 0; j < 4; ++j) { int xx = ws[j]; ws[j] = r; r += xx; }
        }
        __syncthreads();
        int excl = s - v + ws[w] + pre;
        if (i0 < N_NODES) p.row_start[i0] = excl;
        if (i1 < N_NODES) p.row_start[i1] = excl + c0;
    }
    grid.sync();

    // P5: scatter edges into CSR order
    for (int e = tid; e < N_EDGES; e += NTHREADS) {
        int d = p.dst[e];
        int pos = p.row_start[d] + atomicAdd(&p.fill[d], 1);
        int s = p.src[e];
        p.e_pack[pos] = make_int2(s, __float_as_int(p.dinv[s]));
    }
    grid.sync();

    // P6: fused layer 1 (agg(x) + gemm1 + bn + relu) -> H16
    for (int base = 0; base < N_NODES * 8; base += NTHREADS) {
        int gid = base + tid;
        int i = gid >> 3, k = gid & 7;
        bool act = (i < N_NODES);
        float acc = 0.f;
        if (act && k < IN_D) {
            int beg = p.row_start[i], end = p.row_start[i + 1];
            for (int e = beg; e < end; ++e) {
                int2 pe = p.e_pack[e];
                acc = fmaf(__int_as_float(pe.y), p.x[pe.x * IN_D + k], acc);
            }
            float di = p.dinv[i];
            acc = di * (acc + di * p.x[i * IN_D + k]);
        }
        int gbase = lane & ~7;
        float a0 = __shfl(acc, gbase + 0);
        float a1 = __shfl(acc, gbase + 1);
        float a2 = __shfl(acc, gbase + 2);
        float a3 = __shfl(acc, gbase + 3);
        float a4 = __shfl(acc, gbase + 4);
        if (act) {
            int f0 = k * 16;
            #pragma unroll
            for (int u = 0; u < 8; ++u) {
                int fa = f0 + u * 2, fb = fa + 1;
                float va = p.b1[fa], vb = p.b1[fb];
                va = fmaf(a0, p.W1[0 * HID + fa], va); vb = fmaf(a0, p.W1[0 * HID + fb], vb);
                va = fmaf(a1, p.W1[1 * HID + fa], va); vb = fmaf(a1, p.W1[1 * HID + fb], vb);
                va = fmaf(a2, p.W1[2 * HID + fa], va); vb = fmaf(a2, p.W1[2 * HID + fb], vb);
                va = fmaf(a3, p.W1[3 * HID + fa], va); vb = fmaf(a3, p.W1[3 * HID + fb], vb);
                va = fmaf(a4, p.W1[4 * HID + fa], va); vb = fmaf(a4, p.W1[4 * HID + fb], vb);
                va = fmaf(va, p.g1[fa] * rs, p.be1[fa]);
                vb = fmaf(vb, p.g1[fb] * rs, p.be1[fb]);
                va = va > 0.f ? va : 0.f;
                vb = vb > 0.f ? vb : 0.f;
                p.H16[(size_t)i * 64 + k * 8 + u] = __floats2half2_rn(va, vb);
            }
        }
    }
    grid.sync();

    // P7: layer-2 aggregation -> A16
    agg_body<NWAVES>(p.H16, p.dinv, p.row_start, p.e_pack, p.A16, gw, lane);
    grid.sync();

    // P8: layer-2 MFMA gemm -> H16 (fp16)
    gemm_body<GRID>((const _Float16*)p.A16, p.Wt2, p.b2, p.g2, p.be2,
                    nullptr, (_Float16*)p.H16, b, t, rs);
    grid.sync();

    // P9: layer-3 aggregation -> A16
    agg_body<NWAVES>(p.H16, p.dinv, p.row_start, p.e_pack, p.A16, gw, lane);
    grid.sync();

    // P10: layer-3 MFMA gemm -> bufA (fp32)
    gemm_body<GRID>((const _Float16*)p.A16, p.Wt3, p.b3, p.g3, p.be3,
                    p.bufA, nullptr, b, t, rs);
    grid.sync();

    // P11: global mean-pool partial sums (batch sorted; run-compressed atomics)
    for (int c = b; c * 64 < N_NODES; c += GRID) {
        int f = t & 127, hv = t >> 7;
        int n0 = c * 64 + hv;
        int nend = min(c * 64 + 64, N_NODES);
        float acc = 0.f, cf = 0.f;
        int cur = -1;
        for (int n = n0; n < nend; n += 2) {
            int gi = p.batch[n];
            if (gi != cur) {
                if (cur >= 0) {
                    atomicAdd(&p.psum[cur * HID + f], acc);
                    if (f == 0) atomicAdd(&p.pcnt[cur], cf);
                }
                acc = 0.f; cf = 0.f; cur = gi;
            }
            acc += p.bufA[(size_t)n * HID + f];
            cf += 1.f;
        }
        if (cur >= 0) {
            atomicAdd(&p.psum[cur * HID + f], acc);
            if (f == 0) atomicAdd(&p.pcnt[cur], cf);
        }
    }
    grid.sync();

    // P12: projection
    if (b < N_GRAPHS && t < EMB) {
        int gi = b, e = t;
        float inv = 1.0f / fmaxf(p.pcnt[gi], 1.0f);
        float acc = p.bp[e];
        #pragma unroll 8
        for (int f = 0; f < HID; ++f)
            acc = fmaf(p.psum[gi * HID + f] * inv, p.Wp[f * EMB + e], acc);
        p.out[gi * EMB + e] = acc;
    }
}

// ================= fallback multi-kernel path (R4, proven) =================

__global__ void k_count(const int* __restrict__ dst, int* __restrict__ cnt) {
    int e = blockIdx.x * blockDim.x + threadIdx.x;
    if (e < N_EDGES) atomicAdd(&cnt[dst[e]], 1);
}

__global__ void k_chunksum(const int* __restrict__ cnt, int* __restrict__ csum,
                           float* __restrict__ dinv) {
    __shared__ int sh[256];
    int b = blockIdx.x, t = threadIdx.x;
    int i0 = b * CHUNK + t, i1 = i0 + 256;
    int v = 0;
    if (i0 < N_NODES) { int c = cnt[i0]; v += c; dinv[i0] = rsqrtf((float)c + 1.0f); }
    if (i1 < N_NODES) { int c = cnt[i1]; v += c; dinv[i1] = rsqrtf((float)c + 1.0f); }
    sh[t] = v; __syncthreads();
    for (int off = 128; off > 0; off >>= 1) {
        if (t < off) sh[t] += sh[t + off];
        __syncthreads();
    }
    if (t == 0) csum[b] = sh[0];
}

__global__ void k_scanchunks(int* __restrict__ csum, int* __restrict__ row_start) {
    int lane = threadIdx.x;
    int v0 = (lane < NCHUNK) ? csum[lane] : 0;
    int v1 = (lane + 64 < NCHUNK) ? csum[lane + 64] : 0;
    int s0 = v0;
    #pragma unroll
    for (int off = 1; off < 64; off <<= 1) {
        int u = __shfl_up(s0, off);
        if (lane >= off) s0 += u;
    }
    int tot0 = __shfl(s0, 63);
    int s1 = v1;
    #pragma unroll
    for (int off = 1; off < 64; off <<= 1) {
        int u = __shfl_up(s1, off);
        if (lane >= off) s1 += u;
    }
    if (lane < NCHUNK) csum[lane] = s0 - v0;
    if (lane + 64 < NCHUNK) csum[lane + 64] = tot0 + s1 - v1;
    if (lane == 0) row_start[N_NODES] = N_EDGES;
}

__global__ void k_scan(const int* __restrict__ cnt, const int* __restrict__ csum,
                       int* __restrict__ row_start) {
    __shared__ int ws[8];
    int b = blockIdx.x, t = threadIdx.x;
    int lane = t & 63, w = t >> 6;
    int i = b * CHUNK + t;
    int v = (i < N_NODES) ? cnt[i] : 0;
    int s = v;
    #pragma unroll
    for (int off = 1; off < 64; off <<= 1) {
        int u = __shfl_up(s, off);
        if (lane >= off) s += u;
    }
    if (lane == 63) ws[w] = s;
    __syncthreads();
    if (w == 0) {
        int x = (lane < 8) ? ws[lane] : 0;
        int sx = x;
        #pragma unroll
        for (int off = 1; off < 8; off <<= 1) {
            int u = __shfl_up(sx, off);
            if (lane >= off) sx += u;
        }
        if (lane < 8) ws[lane] = sx - x;
    }
    __syncthreads();
    if (i < N_NODES) row_start[i] = s - v + ws[w] + csum[b];
}

__global__ void k_scatter(const int* __restrict__ src, const int* __restrict__ dst,
                          const float* __restrict__ dinv,
                          const int* __restrict__ row_start, int* __restrict__ fill,
                          int2* __restrict__ e_pack) {
    int e = blockIdx.x * blockDim.x + threadIdx.x;
    if (e >= N_EDGES) return;
    int d = dst[e];
    int pos = row_start[d] + atomicAdd(&fill[d], 1);
    int s = src[e];
    e_pack[pos] = make_int2(s, __float_as_int(dinv[s]));
}

__global__ void k_w2h(const float* __restrict__ W2, const float* __restrict__ W3,
                      _Float16* __restrict__ Wt2, _Float16* __restrict__ Wt3) {
    int id = blockIdx.x * blockDim.x + threadIdx.x;
    const float* W = (id < 16384) ? W2 : W3;
    _Float16* O = (id < 16384) ? Wt2 : Wt3;
    int rem = id & 16383;
    int k = rem & 127, f = rem >> 7;
    O[rem] = (_Float16)W[k * 128 + f];
}

__global__ __launch_bounds__(256) void k_agg5g1(
        const float* __restrict__ x, const float* __restrict__ dinv,
        const int* __restrict__ row_start, const int2* __restrict__ e_pack,
        const float* __restrict__ W1, const float* __restrict__ b1,
        const float* __restrict__ g1, const float* __restrict__ be1,
        __half2* __restrict__ H16) {
    int gid = blockIdx.x * blockDim.x + threadIdx.x;
    int i = gid >> 3, k = gid & 7;
    if (i >= N_NODES) return;
    float acc = 0.f;
    if (k < IN_D) {
        int beg = row_start[i], end = row_start[i + 1];
        for (int e = beg; e < end; ++e) {
            int2 p = e_pack[e];
            acc = fmaf(__int_as_float(p.y), x[p.x * IN_D + k], acc);
        }
        float di = dinv[i];
        acc = di * (acc + di * x[i * IN_D + k]);
    }
    int lane = threadIdx.x & 63;
    int base = lane & ~7;
    float a0 = __shfl(acc, base + 0);
    float a1 = __shfl(acc, base + 1);
    float a2 = __shfl(acc, base + 2);
    float a3 = __shfl(acc, base + 3);
    float a4 = __shfl(acc, base + 4);
    const float rs = rsqrtf(1.0f + 1e-5f);
    int f0 = k * 16;
    #pragma unroll
    for (int u = 0; u < 8; ++u) {
        int fa = f0 + u * 2, fb = fa + 1;
        float va = b1[fa], vb = b1[fb];
        va = fmaf(a0, W1[0 * HID + fa], va); vb = fmaf(a0, W1[0 * HID + fb], vb);
        va = fmaf(a1, W1[1 * HID + fa], va); vb = fmaf(a1, W1[1 * HID + fb], vb);
        va = fmaf(a2, W1[2 * HID + fa], va); vb = fmaf(a2, W1[2 * HID + fb], vb);
        va = fmaf(a3, W1[3 * HID + fa], va); vb = fmaf(a3, W1[3 * HID + fb], vb);
        va = fmaf(a4, W1[4 * HID + fa], va); vb = fmaf(a4, W1[4 * HID + fb], vb);
        va = fmaf(va, g1[fa] * rs, be1[fa]);
        vb = fmaf(vb, g1[fb] * rs, be1[fb]);
        va = va > 0.f ? va : 0.f;
        vb = vb > 0.f ? vb : 0.f;
        H16[(size_t)i * 64 + k * 8 + u] = __floats2half2_rn(va, vb);
    }
}

__global__ __launch_bounds__(256) void k_agg128h(
        const __half2* __restrict__ H2, const float* __restrict__ dinv,
        const int* __restrict__ row_start, const int2* __restrict__ e_pack,
        __half2* __restrict__ A16) {
    int wid = (blockIdx.x * blockDim.x + threadIdx.x) >> 6;
    int lane = threadIdx.x & 63;
    if (wid >= N_NODES) return;
    agg_body<0x7FFFFFFF>(H2, dinv, row_start, e_pack, A16, wid, lane);
}

template <bool OUT16>
__global__ __launch_bounds__(256) void k_gemmM(
        const _Float16* __restrict__ A16, const _Float16* __restrict__ Wt16,
        const float* __restrict__ b, const float* __restrict__ g,
        const float* __restrict__ be,
        float* __restrict__ outF, _Float16* __restrict__ outH) {
    const float rs = rsqrtf(1.0f + 1e-5f);
    gemm_body<0x7FFFFFFF>(A16, Wt16, b, g, be,
                          OUT16 ? nullptr : outF, OUT16 ? outH : nullptr,
                          blockIdx.x, threadIdx.x, rs);
}

#define PCHUNK 64
__global__ __launch_bounds__(256) void k_pool(
        const float* __restrict__ H, const int* __restrict__ batch,
        float* __restrict__ sums, float* __restrict__ cntf) {
    int b = blockIdx.x, t = threadIdx.x;
    int f = t & 127, hv = t >> 7;
    int n0 = b * PCHUNK + hv;
    int nend = min(b * PCHUNK + PCHUNK, N_NODES);
    float acc = 0.f, c = 0.f;
    int cur = -1;
    for (int n = n0; n < nend; n += 2) {
        int gi = batch[n];
        if (gi != cur) {
            if (cur >= 0) {
                atomicAdd(&sums[cur * HID + f], acc);
                if (f == 0) atomicAdd(&cntf[cur], c);
            }
            acc = 0.f; c = 0.f; cur = gi;
        }
        acc += H[(size_t)n * HID + f];
        c += 1.f;
    }
    if (cur >= 0) {
        atomicAdd(&sums[cur * HID + f], acc);
        if (f == 0) atomicAdd(&cntf[cur], c);
    }
}

__global__ void k_final(const float* __restrict__ sums, const float* __restrict__ cntf,
                        const float* __restrict__ Wp, const float* __restrict__ bp,
                        float* __restrict__ out) {
    int gi = blockIdx.x, e = threadIdx.x;
    float inv = 1.0f / fmaxf(cntf[gi], 1.0f);
    float acc = bp[e];
    #pragma unroll 8
    for (int f = 0; f < HID; ++f)
        acc = fmaf(sums[gi * HID + f] * inv, Wp[f * EMB + e], acc);
    out[gi * EMB + e] = acc;
}

// ---------- launcher ----------

extern "C" void kernel_launch(void* const* d_in, const int* in_sizes, int n_in,
                              void* d_out, int out_size, void* d_ws, size_t ws_size,
                              hipStream_t stream) {
    char* ws = (char*)d_ws;
    size_t o = 0;
    auto alloc = [&](size_t bytes) {
        void* pp = ws + o;
        o += bytes;
        o = (o + 255) & ~255ull;
        return pp;
    };

    Params p;
    p.x   = (const float*)d_in[0];
    p.src = (const int*)d_in[1];
    p.dst = (const int*)d_in[2];
    p.batch = (const int*)d_in[3];
    p.W1 = (const float*)d_in[4];  p.b1 = (const float*)d_in[5];
    p.W2 = (const float*)d_in[6];  p.b2 = (const float*)d_in[7];
    p.W3 = (const float*)d_in[8];  p.b3 = (const float*)d_in[9];
    p.g1 = (const float*)d_in[10]; p.be1 = (const float*)d_in[11];
    p.g2 = (const float*)d_in[12]; p.be2 = (const float*)d_in[13];
    p.g3 = (const float*)d_in[14]; p.be3 = (const float*)d_in[15];
    p.Wp = (const float*)d_in[16]; p.bp = (const float*)d_in[17];
    p.out = (float*)d_out;

    p.cnt       = (int*)alloc(N_NODES * 4);
    p.fill      = (int*)alloc(N_NODES * 4);
    p.row_start = (int*)alloc((N_NODES + 1) * 4);
    p.csum      = (int*)alloc(NCHUNK * 4);
    p.dinv      = (float*)alloc(N_NODES * 4);
    p.e_pack    = (int2*)alloc((size_t)N_EDGES * 8);
    p.Wt2       = (_Float16*)alloc(HID * HID * 2);
    p.Wt3       = (_Float16*)alloc(HID * HID * 2);
    p.H16       = (__half2*)alloc((size_t)(N_NODES + 64) * HID * 2);
    p.A16       = (__half2*)alloc((size_t)(N_NODES + 64) * HID * 2);
    p.bufA      = (float*)alloc((size_t)N_NODES * HID * 4);
    p.psum      = (float*)alloc(N_GRAPHS * HID * 4);
    p.pcnt      = (float*)alloc(N_GRAPHS * 4);

    Params pl = p;
    void* args[] = {&pl};
    hipError_t err = hipLaunchCooperativeKernel((const void*)k_mega, dim3(GRID),
                                                dim3(BLOCK), args, 0, stream);
    if (err != hipSuccess) {
        // fallback: proven multi-kernel path (identical math)
        hipMemsetAsync(p.cnt, 0, N_NODES * 4, stream);
        hipMemsetAsync(p.fill, 0, N_NODES * 4, stream);
        k_w2h<<<128, 256, 0, stream>>>(p.W2, p.W3, p.Wt2, p.Wt3);
        k_count<<<(N_EDGES + 255) / 256, 256, 0, stream>>>(p.dst, p.cnt);
        k_chunksum<<<NCHUNK, 256, 0, stream>>>(p.cnt, p.csum, p.dinv);
        k_scanchunks<<<1, 64, 0, stream>>>(p.csum, p.row_start);
        k_scan<<<NCHUNK, CHUNK, 0, stream>>>(p.cnt, p.csum, p.row_start);
        k_scatter<<<(N_EDGES + 255) / 256, 256, 0, stream>>>(p.src, p.dst, p.dinv,
                                                             p.row_start, p.fill, p.e_pack);
        k_agg5g1<<<(N_NODES * 8 + 255) / 256, 256, 0, stream>>>(p.x, p.dinv, p.row_start,
                                                                p.e_pack, p.W1, p.b1,
                                                                p.g1, p.be1, p.H16);
        k_agg128h<<<(N_NODES * 64 + 255) / 256, 256, 0, stream>>>(p.H16, p.dinv,
                                                                  p.row_start, p.e_pack,
                                                                  p.A16);
        k_gemmM<true><<<(N_NODES + 63) / 64, 256, 0, stream>>>((const _Float16*)p.A16,
                                                               p.Wt2, p.b2, p.g2, p.be2,
                                                               nullptr, (_Float16*)p.H16);
        k_agg128h<<<(N_NODES * 64 + 255) / 256, 256, 0, stream>>>(p.H16, p.dinv,
                                                                  p.row_start, p.e_pack,
                                                                  p.A16);
        k_gemmM<false><<<(N_NODES + 63) / 64, 256, 0, stream>>>((const _Float16*)p.A16,
                                                                p.Wt3, p.b3, p.g3, p.be3,
                                                                p.bufA, nullptr);
        hipMemsetAsync(p.psum, 0, (N_GRAPHS * HID + N_GRAPHS) * 4, stream);
        k_pool<<<(N_NODES + PCHUNK - 1) / PCHUNK, 256, 0, stream>>>(p.bufA, p.batch,
                                                                    p.psum, p.pcnt);
        k_final<<<N_GRAPHS, EMB, 0, stream>>>(p.psum, p.pcnt, p.Wp, p.bp, p.out);
    }
}

// Round 7
// 553.291 us; speedup vs baseline: 1.5638x; 1.5638x over previous
//
#include <hip/hip_runtime.h>
#include <hip/hip_fp16.h>

#define N_NODES 50000
#define N_EDGES 600000
#define N_GRAPHS 64
#define IN_D 5
#define HID 128
#define EMB 64

#define CHUNK 512
#define NCHUNK ((N_NODES + CHUNK - 1) / CHUNK)   // 98

typedef _Float16 half8 __attribute__((ext_vector_type(8)));
typedef float float4v __attribute__((ext_vector_type(4)));

// ---------- 1. init: zero everything + fp16-transpose W2/W3 ----------

__global__ __launch_bounds__(256) void k_init(
        int* __restrict__ cnt, int* __restrict__ fill, float* __restrict__ psum,
        int* __restrict__ pcnt_i,
        const float* __restrict__ W2, const float* __restrict__ W3,
        _Float16* __restrict__ Wt2, _Float16* __restrict__ Wt3) {
    int tid = blockIdx.x * blockDim.x + threadIdx.x;
    int nt = gridDim.x * blockDim.x;
    for (int i = tid; i < N_NODES; i += nt) { cnt[i] = 0; fill[i] = 0; }
    for (int i = tid; i < N_GRAPHS * HID; i += nt) psum[i] = 0.f;
    if (tid < N_GRAPHS) pcnt_i[tid] = 0;
    for (int i = tid; i < 2 * HID * HID; i += nt) {
        int rem = i & (HID * HID - 1);
        int k = rem & 127, f = rem >> 7;
        if (i < HID * HID) Wt2[rem] = (_Float16)W2[k * HID + f];
        else               Wt3[rem] = (_Float16)W3[k * HID + f];
    }
}

// ---------- 2. degree count + batch histogram ----------

__global__ __launch_bounds__(256) void k_count(
        const int* __restrict__ dst, int* __restrict__ cnt,
        const int* __restrict__ batch, int* __restrict__ pcnt_i) {
    int tid = blockIdx.x * blockDim.x + threadIdx.x;
    int nt = gridDim.x * blockDim.x;
    for (int e = tid; e < N_EDGES; e += nt) atomicAdd(&cnt[dst[e]], 1);
    for (int n = tid; n < N_NODES; n += nt) atomicAdd(&pcnt_i[batch[n]], 1);
}

// ---------- 3. per-chunk sums + dinv ----------

__global__ void k_chunksum(const int* __restrict__ cnt, int* __restrict__ csum,
                           float* __restrict__ dinv) {
    __shared__ int sh[256];
    int b = blockIdx.x, t = threadIdx.x;
    int i0 = b * CHUNK + t, i1 = i0 + 256;
    int v = 0;
    if (i0 < N_NODES) { int c = cnt[i0]; v += c; dinv[i0] = rsqrtf((float)c + 1.0f); }
    if (i1 < N_NODES) { int c = cnt[i1]; v += c; dinv[i1] = rsqrtf((float)c + 1.0f); }
    sh[t] = v; __syncthreads();
    for (int off = 128; off > 0; off >>= 1) {
        if (t < off) sh[t] += sh[t + off];
        __syncthreads();
    }
    if (t == 0) csum[b] = sh[0];
}

// ---------- 4. per-chunk exclusive scan -> row_start ----------
// each block wave-reduces csum[0..b-1] itself (no separate chunk-scan dispatch)

__global__ void k_scan(const int* __restrict__ cnt, const int* __restrict__ csum,
                       int* __restrict__ row_start) {
    __shared__ int ws[4];
    int b = blockIdx.x, t = threadIdx.x;
    int lane = t & 63, w = t >> 6;

    int pre = 0;
    for (int j = lane; j < b; j += 64) pre += csum[j];
    #pragma unroll
    for (int off = 32; off > 0; off >>= 1) pre += __shfl_down(pre, off);
    pre = __shfl(pre, 0);

    int base = b * CHUNK;
    int i0 = base + 2 * t, i1 = i0 + 1;
    int c0 = (i0 < N_NODES) ? cnt[i0] : 0;
    int c1 = (i1 < N_NODES) ? cnt[i1] : 0;
    int v = c0 + c1;
    int s = v;
    #pragma unroll
    for (int off = 1; off < 64; off <<= 1) {
        int u = __shfl_up(s, off);
        if (lane >= off) s += u;
    }
    if (lane == 63) ws[w] = s;
    __syncthreads();
    if (t == 0) {
        int r = 0;
        #pragma unroll
        for (int j = 0; j < 4; ++j) { int xx = ws[j]; ws[j] = r; r += xx; }
    }
    __syncthreads();
    int excl = s - v + ws[w] + pre;
    if (i0 < N_NODES) row_start[i0] = excl;
    if (i1 < N_NODES) row_start[i1] = excl + c0;
    if (b == 0 && t == 0) row_start[N_NODES] = N_EDGES;
}

// ---------- 5. scatter edges into CSR order ----------

__global__ __launch_bounds__(256) void k_scatter(
        const int* __restrict__ src, const int* __restrict__ dst,
        const float* __restrict__ dinv, const int* __restrict__ row_start,
        int* __restrict__ fill, int2* __restrict__ e_pack) {
    int e = blockIdx.x * blockDim.x + threadIdx.x;
    if (e >= N_EDGES) return;
    int d = dst[e];
    int pos = row_start[d] + atomicAdd(&fill[d], 1);
    int s = src[e];
    e_pack[pos] = make_int2(s, __float_as_int(dinv[s]));
}

// ---------- 6. fused layer 1: agg(x) + gemm1 + bn + relu -> H16 ----------

__global__ __launch_bounds__(256) void k_agg5g1(
        const float* __restrict__ x, const float* __restrict__ dinv,
        const int* __restrict__ row_start, const int2* __restrict__ e_pack,
        const float* __restrict__ W1, const float* __restrict__ b1,
        const float* __restrict__ g1, const float* __restrict__ be1,
        __half2* __restrict__ H16) {
    int gid = blockIdx.x * blockDim.x + threadIdx.x;
    int i = gid >> 3, k = gid & 7;
    if (i >= N_NODES) return;
    float acc = 0.f;
    if (k < IN_D) {
        int beg = row_start[i], end = row_start[i + 1];
        int e = beg;
        for (; e + 3 < end; e += 4) {
            int2 p0 = e_pack[e];
            int2 p1 = e_pack[e + 1];
            int2 p2 = e_pack[e + 2];
            int2 p3 = e_pack[e + 3];
            float x0 = x[p0.x * IN_D + k];
            float x1 = x[p1.x * IN_D + k];
            float x2 = x[p2.x * IN_D + k];
            float x3 = x[p3.x * IN_D + k];
            acc = fmaf(__int_as_float(p0.y), x0, acc);
            acc = fmaf(__int_as_float(p1.y), x1, acc);
            acc = fmaf(__int_as_float(p2.y), x2, acc);
            acc = fmaf(__int_as_float(p3.y), x3, acc);
        }
        for (; e < end; ++e) {
            int2 p = e_pack[e];
            acc = fmaf(__int_as_float(p.y), x[p.x * IN_D + k], acc);
        }
        float di = dinv[i];
        acc = di * (acc + di * x[i * IN_D + k]);
    }
    int lane = threadIdx.x & 63;
    int base = lane & ~7;
    float a0 = __shfl(acc, base + 0);
    float a1 = __shfl(acc, base + 1);
    float a2 = __shfl(acc, base + 2);
    float a3 = __shfl(acc, base + 3);
    float a4 = __shfl(acc, base + 4);
    const float rs = rsqrtf(1.0f + 1e-5f);
    int f0 = k * 16;
    #pragma unroll
    for (int u = 0; u < 8; ++u) {
        int fa = f0 + u * 2, fb = fa + 1;
        float va = b1[fa], vb = b1[fb];
        va = fmaf(a0, W1[0 * HID + fa], va); vb = fmaf(a0, W1[0 * HID + fb], vb);
        va = fmaf(a1, W1[1 * HID + fa], va); vb = fmaf(a1, W1[1 * HID + fb], vb);
        va = fmaf(a2, W1[2 * HID + fa], va); vb = fmaf(a2, W1[2 * HID + fb], vb);
        va = fmaf(a3, W1[3 * HID + fa], va); vb = fmaf(a3, W1[3 * HID + fb], vb);
        va = fmaf(a4, W1[4 * HID + fa], va); vb = fmaf(a4, W1[4 * HID + fb], vb);
        va = fmaf(va, g1[fa] * rs, be1[fa]);
        vb = fmaf(vb, g1[fb] * rs, be1[fb]);
        va = va > 0.f ? va : 0.f;
        vb = vb > 0.f ? vb : 0.f;
        H16[(size_t)i * 64 + k * 8 + u] = __floats2half2_rn(va, vb);
    }
}

// ---------- 7/9. aggregation over fp16 table -> fp16 A ----------

__global__ __launch_bounds__(256) void k_agg128h(
        const __half2* __restrict__ H2, const float* __restrict__ dinv,
        const int* __restrict__ row_start, const int2* __restrict__ e_pack,
        __half2* __restrict__ A16) {
    int n = (blockIdx.x * blockDim.x + threadIdx.x) >> 6;
    int lane = threadIdx.x & 63;
    if (n >= N_NODES) return;
    float2 acc = make_float2(0.f, 0.f);
    int beg = row_start[n], end = row_start[n + 1];
    int e = beg;
    for (; e + 7 < end; e += 8) {
        int2 p[8];
        float2 h[8];
        #pragma unroll
        for (int u = 0; u < 8; ++u) p[u] = e_pack[e + u];
        #pragma unroll
        for (int u = 0; u < 8; ++u)
            h[u] = __half22float2(H2[(size_t)p[u].x * 64 + lane]);
        #pragma unroll
        for (int u = 0; u < 8; ++u) {
            float w = __int_as_float(p[u].y);
            acc.x = fmaf(w, h[u].x, acc.x);
            acc.y = fmaf(w, h[u].y, acc.y);
        }
    }
    for (; e + 3 < end; e += 4) {
        int2 p[4];
        float2 h[4];
        #pragma unroll
        for (int u = 0; u < 4; ++u) p[u] = e_pack[e + u];
        #pragma unroll
        for (int u = 0; u < 4; ++u)
            h[u] = __half22float2(H2[(size_t)p[u].x * 64 + lane]);
        #pragma unroll
        for (int u = 0; u < 4; ++u) {
            float w = __int_as_float(p[u].y);
            acc.x = fmaf(w, h[u].x, acc.x);
            acc.y = fmaf(w, h[u].y, acc.y);
        }
    }
    for (; e < end; ++e) {
        int2 pe = e_pack[e];
        float w = __int_as_float(pe.y);
        float2 f = __half22float2(H2[(size_t)pe.x * 64 + lane]);
        acc.x = fmaf(w, f.x, acc.x);
        acc.y = fmaf(w, f.y, acc.y);
    }
    float di = dinv[n];
    float2 hs = __half22float2(H2[(size_t)n * 64 + lane]);
    acc.x = fmaf(di, hs.x, acc.x);
    acc.y = fmaf(di, hs.y, acc.y);
    A16[(size_t)n * 64 + lane] = __floats2half2_rn(di * acc.x, di * acc.y);
}

// ---------- 8. layer-2 MFMA gemm -> H16 (fp16) ----------
// A[m=lane&15][k=quad*8+j]; B via f-major Wt; C/D col=lane&15,row=quad*4+reg.

__global__ __launch_bounds__(256) void k_gemm2(
        const _Float16* __restrict__ A16, const _Float16* __restrict__ Wt,
        const float* __restrict__ bb, const float* __restrict__ gg,
        const float* __restrict__ bee, _Float16* __restrict__ outH) {
    int t = threadIdx.x;
    int w = t >> 6, lane = t & 63;
    int quad = lane >> 4, r16 = lane & 15;
    int nb = blockIdx.x * 64 + w * 16;
    const float rs = rsqrtf(1.0f + 1e-5f);
    const half8* Arow = (const half8*)(A16 + (size_t)(nb + r16) * 128);
    half8 a[4];
    #pragma unroll
    for (int kb = 0; kb < 4; ++kb) a[kb] = Arow[kb * 4 + quad];
    #pragma unroll
    for (int ft = 0; ft < 8; ++ft) {
        int f = ft * 16 + r16;
        const half8* Brow = (const half8*)(Wt + (size_t)f * 128);
        float4v acc = {0.f, 0.f, 0.f, 0.f};
        #pragma unroll
        for (int kb = 0; kb < 4; ++kb)
            acc = __builtin_amdgcn_mfma_f32_16x16x32_f16(a[kb], Brow[kb * 4 + quad],
                                                         acc, 0, 0, 0);
        float b0 = bb[f], g0 = gg[f] * rs, e0 = bee[f];
        #pragma unroll
        for (int rr = 0; rr < 4; ++rr) {
            int n = nb + quad * 4 + rr;
            if (n < N_NODES) {
                float v = fmaf(acc[rr] + b0, g0, e0);
                v = v > 0.f ? v : 0.f;
                outH[(size_t)n * 128 + f] = (_Float16)v;
            }
        }
    }
}

// ---------- 10. layer-3 MFMA gemm + fused mean-pool (atomic psum) ----------

__global__ __launch_bounds__(256) void k_gemm3pool(
        const _Float16* __restrict__ A16, const _Float16* __restrict__ Wt,
        const float* __restrict__ bb, const float* __restrict__ gg,
        const float* __restrict__ bee, const int* __restrict__ batch,
        float* __restrict__ psum) {
    int t = threadIdx.x;
    int w = t >> 6, lane = t & 63;
    int quad = lane >> 4, r16 = lane & 15;
    int nb = blockIdx.x * 64 + w * 16;
    const float rs = rsqrtf(1.0f + 1e-5f);
    const half8* Arow = (const half8*)(A16 + (size_t)(nb + r16) * 128);
    half8 a[4];
    #pragma unroll
    for (int kb = 0; kb < 4; ++kb) a[kb] = Arow[kb * 4 + quad];
    int gi4[4];
    #pragma unroll
    for (int rr = 0; rr < 4; ++rr) {
        int n = nb + quad * 4 + rr;
        gi4[rr] = (n < N_NODES) ? batch[n] : -1;
    }
    #pragma unroll
    for (int ft = 0; ft < 8; ++ft) {
        int f = ft * 16 + r16;
        const half8* Brow = (const half8*)(Wt + (size_t)f * 128);
        float4v acc = {0.f, 0.f, 0.f, 0.f};
        #pragma unroll
        for (int kb = 0; kb < 4; ++kb)
            acc = __builtin_amdgcn_mfma_f32_16x16x32_f16(a[kb], Brow[kb * 4 + quad],
                                                         acc, 0, 0, 0);
        float b0 = bb[f], g0 = gg[f] * rs, e0 = bee[f];
        float partial = 0.f;
        int cur = -1;
        #pragma unroll
        for (int rr = 0; rr < 4; ++rr) {
            int gi = gi4[rr];
            if (gi >= 0) {
                float v = fmaf(acc[rr] + b0, g0, e0);
                v = v > 0.f ? v : 0.f;
                if (gi != cur) {
                    if (cur >= 0) atomicAdd(&psum[cur * HID + f], partial);
                    partial = 0.f; cur = gi;
                }
                partial += v;
            }
        }
        if (cur >= 0) atomicAdd(&psum[cur * HID + f], partial);
    }
}

// ---------- 11. projection ----------

__global__ void k_final(const float* __restrict__ psum, const int* __restrict__ pcnt_i,
                        const float* __restrict__ Wp, const float* __restrict__ bp,
                        float* __restrict__ out) {
    int gi = blockIdx.x, e = threadIdx.x;
    float inv = 1.0f / fmaxf((float)pcnt_i[gi], 1.0f);
    float acc = bp[e];
    #pragma unroll 8
    for (int f = 0; f < HID; ++f)
        acc = fmaf(psum[gi * HID + f] * inv, Wp[f * EMB + e], acc);
    out[gi * EMB + e] = acc;
}

// ---------- launcher ----------

extern "C" void kernel_launch(void* const* d_in, const int* in_sizes, int n_in,
                              void* d_out, int out_size, void* d_ws, size_t ws_size,
                              hipStream_t stream) {
    const float* x   = (const float*)d_in[0];
    const int*   src = (const int*)d_in[1];
    const int*   dst = (const int*)d_in[2];
    const int* batch = (const int*)d_in[3];
    const float* W1 = (const float*)d_in[4];
    const float* b1 = (const float*)d_in[5];
    const float* W2 = (const float*)d_in[6];
    const float* b2 = (const float*)d_in[7];
    const float* W3 = (const float*)d_in[8];
    const float* b3 = (const float*)d_in[9];
    const float* g1 = (const float*)d_in[10];
    const float* be1 = (const float*)d_in[11];
    const float* g2 = (const float*)d_in[12];
    const float* be2 = (const float*)d_in[13];
    const float* g3 = (const float*)d_in[14];
    const float* be3 = (const float*)d_in[15];
    const float* Wp = (const float*)d_in[16];
    const float* bp = (const float*)d_in[17];
    float* out = (float*)d_out;

    char* ws = (char*)d_ws;
    size_t o = 0;
    auto alloc = [&](size_t bytes) {
        void* pp = ws + o;
        o += bytes;
        o = (o + 255) & ~255ull;
        return pp;
    };
    int*      cnt       = (int*)alloc(N_NODES * 4);
    int*      fill      = (int*)alloc(N_NODES * 4);
    int*      row_start = (int*)alloc((N_NODES + 1) * 4);
    int*      csum      = (int*)alloc(NCHUNK * 4);
    float*    dinv      = (float*)alloc(N_NODES * 4);
    int2*     e_pack    = (int2*)alloc((size_t)N_EDGES * 8);
    _Float16* Wt2       = (_Float16*)alloc(HID * HID * 2);
    _Float16* Wt3       = (_Float16*)alloc(HID * HID * 2);
    __half2*  H16       = (__half2*)alloc((size_t)(N_NODES + 64) * HID * 2);
    __half2*  A16       = (__half2*)alloc((size_t)(N_NODES + 64) * HID * 2);
    float*    psum      = (float*)alloc(N_GRAPHS * HID * 4);
    int*      pcnt_i    = (int*)alloc(N_GRAPHS * 4);

    k_init<<<512, 256, 0, stream>>>(cnt, fill, psum, pcnt_i, W2, W3, Wt2, Wt3);
    k_count<<<1024, 256, 0, stream>>>(dst, cnt, batch, pcnt_i);
    k_chunksum<<<NCHUNK, 256, 0, stream>>>(cnt, csum, dinv);
    k_scan<<<NCHUNK, 256, 0, stream>>>(cnt, csum, row_start);
    k_scatter<<<(N_EDGES + 255) / 256, 256, 0, stream>>>(src, dst, dinv, row_start,
                                                         fill, e_pack);
    k_agg5g1<<<(N_NODES * 8 + 255) / 256, 256, 0, stream>>>(x, dinv, row_start, e_pack,
                                                            W1, b1, g1, be1, H16);
    k_agg128h<<<(N_NODES * 64 + 255) / 256, 256, 0, stream>>>(H16, dinv, row_start,
                                                              e_pack, A16);
    k_gemm2<<<(N_NODES + 63) / 64, 256, 0, stream>>>((const _Float16*)A16, Wt2,
                                                     b2, g2, be2, (_Float16*)H16);
    k_agg128h<<<(N_NODES * 64 + 255) / 256, 256, 0, stream>>>(H16, dinv, row_start,
                                                              e_pack, A16);
    k_gemm3pool<<<(N_NODES + 63) / 64, 256, 0, stream>>>((const _Float16*)A16, Wt3,
                                                         b3, g3, be3, batch, psum);
    k_final<<<N_GRAPHS, EMB, 0, stream>>>(psum, pcnt_i, Wp, bp, out);
}

// Round 8
// 324.106 us; speedup vs baseline: 2.6696x; 1.7071x over previous
//
#include <hip/hip_runtime.h>
#include <hip/hip_fp16.h>

#define N_NODES 50000
#define N_EDGES 600000
#define N_GRAPHS 64
#define IN_D 5
#define HID 128
#define EMB 64

#define CHUNK 512
#define NCHUNK ((N_NODES + CHUNK - 1) / CHUNK)   // 98

typedef _Float16 half8 __attribute__((ext_vector_type(8)));
typedef float float4v __attribute__((ext_vector_type(4)));

// ---------- 1. init: zero everything + fp16-transpose W2/W3 ----------

__global__ __launch_bounds__(256) void k_init(
        int* __restrict__ cnt, int* __restrict__ fill, float* __restrict__ psum,
        const float* __restrict__ W2, const float* __restrict__ W3,
        _Float16* __restrict__ Wt2, _Float16* __restrict__ Wt3) {
    int tid = blockIdx.x * blockDim.x + threadIdx.x;
    int nt = gridDim.x * blockDim.x;
    for (int i = tid; i < N_NODES; i += nt) { cnt[i] = 0; fill[i] = 0; }
    for (int i = tid; i < N_GRAPHS * HID; i += nt) psum[i] = 0.f;
    for (int i = tid; i < 2 * HID * HID; i += nt) {
        int rem = i & (HID * HID - 1);
        int k = rem & 127, f = rem >> 7;
        if (i < HID * HID) Wt2[rem] = (_Float16)W2[k * HID + f];
        else               Wt3[rem] = (_Float16)W3[k * HID + f];
    }
}

// ---------- 2. degree count (edge atomics only — no batch histogram!) ----------
// R7 lesson: atomicAdd on sorted batch -> 64 hot counters -> 260 us of
// cross-XCD contention. Graph counts now come from binary search in k_final.

__global__ __launch_bounds__(256) void k_count(
        const int* __restrict__ dst, int* __restrict__ cnt) {
    int e = blockIdx.x * blockDim.x + threadIdx.x;
    if (e < N_EDGES) atomicAdd(&cnt[dst[e]], 1);
}

// ---------- 3. per-chunk sums + dinv ----------

__global__ void k_chunksum(const int* __restrict__ cnt, int* __restrict__ csum,
                           float* __restrict__ dinv) {
    __shared__ int sh[256];
    int b = blockIdx.x, t = threadIdx.x;
    int i0 = b * CHUNK + t, i1 = i0 + 256;
    int v = 0;
    if (i0 < N_NODES) { int c = cnt[i0]; v += c; dinv[i0] = rsqrtf((float)c + 1.0f); }
    if (i1 < N_NODES) { int c = cnt[i1]; v += c; dinv[i1] = rsqrtf((float)c + 1.0f); }
    sh[t] = v; __syncthreads();
    for (int off = 128; off > 0; off >>= 1) {
        if (t < off) sh[t] += sh[t + off];
        __syncthreads();
    }
    if (t == 0) csum[b] = sh[0];
}

// ---------- 4. per-chunk exclusive scan -> row_start ----------
// each block wave-reduces csum[0..b-1] itself (no separate chunk-scan dispatch)

__global__ void k_scan(const int* __restrict__ cnt, const int* __restrict__ csum,
                       int* __restrict__ row_start) {
    __shared__ int ws[4];
    int b = blockIdx.x, t = threadIdx.x;
    int lane = t & 63, w = t >> 6;

    int pre = 0;
    for (int j = lane; j < b; j += 64) pre += csum[j];
    #pragma unroll
    for (int off = 32; off > 0; off >>= 1) pre += __shfl_down(pre, off);
    pre = __shfl(pre, 0);

    int base = b * CHUNK;
    int i0 = base + 2 * t, i1 = i0 + 1;
    int c0 = (i0 < N_NODES) ? cnt[i0] : 0;
    int c1 = (i1 < N_NODES) ? cnt[i1] : 0;
    int v = c0 + c1;
    int s = v;
    #pragma unroll
    for (int off = 1; off < 64; off <<= 1) {
        int u = __shfl_up(s, off);
        if (lane >= off) s += u;
    }
    if (lane == 63) ws[w] = s;
    __syncthreads();
    if (t == 0) {
        int r = 0;
        #pragma unroll
        for (int j = 0; j < 4; ++j) { int xx = ws[j]; ws[j] = r; r += xx; }
    }
    __syncthreads();
    int excl = s - v + ws[w] + pre;
    if (i0 < N_NODES) row_start[i0] = excl;
    if (i1 < N_NODES) row_start[i1] = excl + c0;
    if (b == 0 && t == 0) row_start[N_NODES] = N_EDGES;
}

// ---------- 5. scatter edges into CSR order ----------

__global__ __launch_bounds__(256) void k_scatter(
        const int* __restrict__ src, const int* __restrict__ dst,
        const float* __restrict__ dinv, const int* __restrict__ row_start,
        int* __restrict__ fill, int2* __restrict__ e_pack) {
    int e = blockIdx.x * blockDim.x + threadIdx.x;
    if (e >= N_EDGES) return;
    int d = dst[e];
    int pos = row_start[d] + atomicAdd(&fill[d], 1);
    int s = src[e];
    e_pack[pos] = make_int2(s, __float_as_int(dinv[s]));
}

// ---------- 6. fused layer 1: agg(x) + gemm1 + bn + relu -> H16 ----------

__global__ __launch_bounds__(256) void k_agg5g1(
        const float* __restrict__ x, const float* __restrict__ dinv,
        const int* __restrict__ row_start, const int2* __restrict__ e_pack,
        const float* __restrict__ W1, const float* __restrict__ b1,
        const float* __restrict__ g1, const float* __restrict__ be1,
        __half2* __restrict__ H16) {
    int gid = blockIdx.x * blockDim.x + threadIdx.x;
    int i = gid >> 3, k = gid & 7;
    if (i >= N_NODES) return;
    float acc = 0.f;
    if (k < IN_D) {
        int beg = row_start[i], end = row_start[i + 1];
        int e = beg;
        for (; e + 3 < end; e += 4) {
            int2 p0 = e_pack[e];
            int2 p1 = e_pack[e + 1];
            int2 p2 = e_pack[e + 2];
            int2 p3 = e_pack[e + 3];
            float x0 = x[p0.x * IN_D + k];
            float x1 = x[p1.x * IN_D + k];
            float x2 = x[p2.x * IN_D + k];
            float x3 = x[p3.x * IN_D + k];
            acc = fmaf(__int_as_float(p0.y), x0, acc);
            acc = fmaf(__int_as_float(p1.y), x1, acc);
            acc = fmaf(__int_as_float(p2.y), x2, acc);
            acc = fmaf(__int_as_float(p3.y), x3, acc);
        }
        for (; e < end; ++e) {
            int2 p = e_pack[e];
            acc = fmaf(__int_as_float(p.y), x[p.x * IN_D + k], acc);
        }
        float di = dinv[i];
        acc = di * (acc + di * x[i * IN_D + k]);
    }
    int lane = threadIdx.x & 63;
    int base = lane & ~7;
    float a0 = __shfl(acc, base + 0);
    float a1 = __shfl(acc, base + 1);
    float a2 = __shfl(acc, base + 2);
    float a3 = __shfl(acc, base + 3);
    float a4 = __shfl(acc, base + 4);
    const float rs = rsqrtf(1.0f + 1e-5f);
    int f0 = k * 16;
    #pragma unroll
    for (int u = 0; u < 8; ++u) {
        int fa = f0 + u * 2, fb = fa + 1;
        float va = b1[fa], vb = b1[fb];
        va = fmaf(a0, W1[0 * HID + fa], va); vb = fmaf(a0, W1[0 * HID + fb], vb);
        va = fmaf(a1, W1[1 * HID + fa], va); vb = fmaf(a1, W1[1 * HID + fb], vb);
        va = fmaf(a2, W1[2 * HID + fa], va); vb = fmaf(a2, W1[2 * HID + fb], vb);
        va = fmaf(a3, W1[3 * HID + fa], va); vb = fmaf(a3, W1[3 * HID + fb], vb);
        va = fmaf(a4, W1[4 * HID + fa], va); vb = fmaf(a4, W1[4 * HID + fb], vb);
        va = fmaf(va, g1[fa] * rs, be1[fa]);
        vb = fmaf(vb, g1[fb] * rs, be1[fb]);
        va = va > 0.f ? va : 0.f;
        vb = vb > 0.f ? vb : 0.f;
        H16[(size_t)i * 64 + k * 8 + u] = __floats2half2_rn(va, vb);
    }
}

// ---------- 7/9. aggregation over fp16 table -> fp16 A ----------

__global__ __launch_bounds__(256) void k_agg128h(
        const __half2* __restrict__ H2, const float* __restrict__ dinv,
        const int* __restrict__ row_start, const int2* __restrict__ e_pack,
        __half2* __restrict__ A16) {
    int n = (blockIdx.x * blockDim.x + threadIdx.x) >> 6;
    int lane = threadIdx.x & 63;
    if (n >= N_NODES) return;
    float2 acc = make_float2(0.f, 0.f);
    int beg = row_start[n], end = row_start[n + 1];
    int e = beg;
    for (; e + 7 < end; e += 8) {
        int2 p[8];
        float2 h[8];
        #pragma unroll
        for (int u = 0; u < 8; ++u) p[u] = e_pack[e + u];
        #pragma unroll
        for (int u = 0; u < 8; ++u)
            h[u] = __half22float2(H2[(size_t)p[u].x * 64 + lane]);
        #pragma unroll
        for (int u = 0; u < 8; ++u) {
            float w = __int_as_float(p[u].y);
            acc.x = fmaf(w, h[u].x, acc.x);
            acc.y = fmaf(w, h[u].y, acc.y);
        }
    }
    for (; e + 3 < end; e += 4) {
        int2 p[4];
        float2 h[4];
        #pragma unroll
        for (int u = 0; u < 4; ++u) p[u] = e_pack[e + u];
        #pragma unroll
        for (int u = 0; u < 4; ++u)
            h[u] = __half22float2(H2[(size_t)p[u].x * 64 + lane]);
        #pragma unroll
        for (int u = 0; u < 4; ++u) {
            float w = __int_as_float(p[u].y);
            acc.x = fmaf(w, h[u].x, acc.x);
            acc.y = fmaf(w, h[u].y, acc.y);
        }
    }
    for (; e < end; ++e) {
        int2 pe = e_pack[e];
        float w = __int_as_float(pe.y);
        float2 f = __half22float2(H2[(size_t)pe.x * 64 + lane]);
        acc.x = fmaf(w, f.x, acc.x);
        acc.y = fmaf(w, f.y, acc.y);
    }
    float di = dinv[n];
    float2 hs = __half22float2(H2[(size_t)n * 64 + lane]);
    acc.x = fmaf(di, hs.x, acc.x);
    acc.y = fmaf(di, hs.y, acc.y);
    A16[(size_t)n * 64 + lane] = __floats2half2_rn(di * acc.x, di * acc.y);
}

// ---------- 8. layer-2 MFMA gemm -> H16 (fp16) ----------
// A[m=lane&15][k=quad*8+j]; B via f-major Wt; C/D col=lane&15,row=quad*4+reg.

__global__ __launch_bounds__(256) void k_gemm2(
        const _Float16* __restrict__ A16, const _Float16* __restrict__ Wt,
        const float* __restrict__ bb, const float* __restrict__ gg,
        const float* __restrict__ bee, _Float16* __restrict__ outH) {
    int t = threadIdx.x;
    int w = t >> 6, lane = t & 63;
    int quad = lane >> 4, r16 = lane & 15;
    int nb = blockIdx.x * 64 + w * 16;
    const float rs = rsqrtf(1.0f + 1e-5f);
    const half8* Arow = (const half8*)(A16 + (size_t)(nb + r16) * 128);
    half8 a[4];
    #pragma unroll
    for (int kb = 0; kb < 4; ++kb) a[kb] = Arow[kb * 4 + quad];
    #pragma unroll
    for (int ft = 0; ft < 8; ++ft) {
        int f = ft * 16 + r16;
        const half8* Brow = (const half8*)(Wt + (size_t)f * 128);
        float4v acc = {0.f, 0.f, 0.f, 0.f};
        #pragma unroll
        for (int kb = 0; kb < 4; ++kb)
            acc = __builtin_amdgcn_mfma_f32_16x16x32_f16(a[kb], Brow[kb * 4 + quad],
                                                         acc, 0, 0, 0);
        float b0 = bb[f], g0 = gg[f] * rs, e0 = bee[f];
        #pragma unroll
        for (int rr = 0; rr < 4; ++rr) {
            int n = nb + quad * 4 + rr;
            if (n < N_NODES) {
                float v = fmaf(acc[rr] + b0, g0, e0);
                v = v > 0.f ? v : 0.f;
                outH[(size_t)n * 128 + f] = (_Float16)v;
            }
        }
    }
}

// ---------- 10. layer-3 MFMA gemm + fused mean-pool (run-compressed atomics) ----------

__global__ __launch_bounds__(256) void k_gemm3pool(
        const _Float16* __restrict__ A16, const _Float16* __restrict__ Wt,
        const float* __restrict__ bb, const float* __restrict__ gg,
        const float* __restrict__ bee, const int* __restrict__ batch,
        float* __restrict__ psum) {
    int t = threadIdx.x;
    int w = t >> 6, lane = t & 63;
    int quad = lane >> 4, r16 = lane & 15;
    int nb = blockIdx.x * 64 + w * 16;
    const float rs = rsqrtf(1.0f + 1e-5f);
    const half8* Arow = (const half8*)(A16 + (size_t)(nb + r16) * 128);
    half8 a[4];
    #pragma unroll
    for (int kb = 0; kb < 4; ++kb) a[kb] = Arow[kb * 4 + quad];
    int gi4[4];
    #pragma unroll
    for (int rr = 0; rr < 4; ++rr) {
        int n = nb + quad * 4 + rr;
        gi4[rr] = (n < N_NODES) ? batch[n] : -1;
    }
    #pragma unroll
    for (int ft = 0; ft < 8; ++ft) {
        int f = ft * 16 + r16;
        const half8* Brow = (const half8*)(Wt + (size_t)f * 128);
        float4v acc = {0.f, 0.f, 0.f, 0.f};
        #pragma unroll
        for (int kb = 0; kb < 4; ++kb)
            acc = __builtin_amdgcn_mfma_f32_16x16x32_f16(a[kb], Brow[kb * 4 + quad],
                                                         acc, 0, 0, 0);
        float b0 = bb[f], g0 = gg[f] * rs, e0 = bee[f];
        float partial = 0.f;
        int cur = -1;
        #pragma unroll
        for (int rr = 0; rr < 4; ++rr) {
            int gi = gi4[rr];
            if (gi >= 0) {
                float v = fmaf(acc[rr] + b0, g0, e0);
                v = v > 0.f ? v : 0.f;
                if (gi != cur) {
                    if (cur >= 0) atomicAdd(&psum[cur * HID + f], partial);
                    partial = 0.f; cur = gi;
                }
                partial += v;
            }
        }
        if (cur >= 0) atomicAdd(&psum[cur * HID + f], partial);
    }
}

// ---------- 11. projection (+ graph counts via binary search, no atomics) ----------

__device__ __forceinline__ int lower_bound_batch(const int* __restrict__ batch, int val) {
    int lo = 0, hi = N_NODES;
    while (lo < hi) {
        int mid = (lo + hi) >> 1;
        if (batch[mid] < val) lo = mid + 1;
        else hi = mid;
    }
    return lo;
}

__global__ void k_final(const float* __restrict__ psum, const int* __restrict__ batch,
                        const float* __restrict__ Wp, const float* __restrict__ bp,
                        float* __restrict__ out) {
    int gi = blockIdx.x, e = threadIdx.x;
    int lane = e & 63;
    int r = 0;
    if (lane < 2) r = lower_bound_batch(batch, gi + lane);
    int c0 = __shfl(r, 0), c1 = __shfl(r, 1);
    float inv = 1.0f / fmaxf((float)(c1 - c0), 1.0f);
    float acc = bp[e];
    #pragma unroll 8
    for (int f = 0; f < HID; ++f)
        acc = fmaf(psum[gi * HID + f] * inv, Wp[f * EMB + e], acc);
    out[gi * EMB + e] = acc;
}

// ---------- launcher ----------

extern "C" void kernel_launch(void* const* d_in, const int* in_sizes, int n_in,
                              void* d_out, int out_size, void* d_ws, size_t ws_size,
                              hipStream_t stream) {
    const float* x   = (const float*)d_in[0];
    const int*   src = (const int*)d_in[1];
    const int*   dst = (const int*)d_in[2];
    const int* batch = (const int*)d_in[3];
    const float* W1 = (const float*)d_in[4];
    const float* b1 = (const float*)d_in[5];
    const float* W2 = (const float*)d_in[6];
    const float* b2 = (const float*)d_in[7];
    const float* W3 = (const float*)d_in[8];
    const float* b3 = (const float*)d_in[9];
    const float* g1 = (const float*)d_in[10];
    const float* be1 = (const float*)d_in[11];
    const float* g2 = (const float*)d_in[12];
    const float* be2 = (const float*)d_in[13];
    const float* g3 = (const float*)d_in[14];
    const float* be3 = (const float*)d_in[15];
    const float* Wp = (const float*)d_in[16];
    const float* bp = (const float*)d_in[17];
    float* out = (float*)d_out;

    char* ws = (char*)d_ws;
    size_t o = 0;
    auto alloc = [&](size_t bytes) {
        void* pp = ws + o;
        o += bytes;
        o = (o + 255) & ~255ull;
        return pp;
    };
    int*      cnt       = (int*)alloc(N_NODES * 4);
    int*      fill      = (int*)alloc(N_NODES * 4);
    int*      row_start = (int*)alloc((N_NODES + 1) * 4);
    int*      csum      = (int*)alloc(NCHUNK * 4);
    float*    dinv      = (float*)alloc(N_NODES * 4);
    int2*     e_pack    = (int2*)alloc((size_t)N_EDGES * 8);
    _Float16* Wt2       = (_Float16*)alloc(HID * HID * 2);
    _Float16* Wt3       = (_Float16*)alloc(HID * HID * 2);
    __half2*  H16       = (__half2*)alloc((size_t)(N_NODES + 64) * HID * 2);
    __half2*  A16       = (__half2*)alloc((size_t)(N_NODES + 64) * HID * 2);
    float*    psum      = (float*)alloc(N_GRAPHS * HID * 4);

    k_init<<<512, 256, 0, stream>>>(cnt, fill, psum, W2, W3, Wt2, Wt3);
    k_count<<<(N_EDGES + 255) / 256, 256, 0, stream>>>(dst, cnt);
    k_chunksum<<<NCHUNK, 256, 0, stream>>>(cnt, csum, dinv);
    k_scan<<<NCHUNK, 256, 0, stream>>>(cnt, csum, row_start);
    k_scatter<<<(N_EDGES + 255) / 256, 256, 0, stream>>>(src, dst, dinv, row_start,
                                                         fill, e_pack);
    k_agg5g1<<<(N_NODES * 8 + 255) / 256, 256, 0, stream>>>(x, dinv, row_start, e_pack,
                                                            W1, b1, g1, be1, H16);
    k_agg128h<<<(N_NODES * 64 + 255) / 256, 256, 0, stream>>>(H16, dinv, row_start,
                                                              e_pack, A16);
    k_gemm2<<<(N_NODES + 63) / 64, 256, 0, stream>>>((const _Float16*)A16, Wt2,
                                                     b2, g2, be2, (_Float16*)H16);
    k_agg128h<<<(N_NODES * 64 + 255) / 256, 256, 0, stream>>>(H16, dinv, row_start,
                                                              e_pack, A16);
    k_gemm3pool<<<(N_NODES + 63) / 64, 256, 0, stream>>>((const _Float16*)A16, Wt3,
                                                         b3, g3, be3, batch, psum);
    k_final<<<N_GRAPHS, EMB, 0, stream>>>(psum, batch, Wp, bp, out);
}

// Round 10
// 293.931 us; speedup vs baseline: 2.9437x; 1.1027x over previous
//
#include <hip/hip_runtime.h>
#include <hip/hip_fp16.h>

#define N_NODES 50000
#define N_EDGES 600000
#define N_GRAPHS 64
#define IN_D 5
#define HID 128
#define EMB 64

#define CHUNK 512
#define NCHUNK ((N_NODES + CHUNK - 1) / CHUNK)   // 98
#define NREP 16          // psum replication factor (contention spread)
#define NLOC 4           // per-block local graph slots (64 sorted nodes span <=2-3)

typedef _Float16 half8 __attribute__((ext_vector_type(8)));
typedef float float4v __attribute__((ext_vector_type(4)));

// ---------- 1. init: zero everything + fp16-transpose W2/W3 ----------

__global__ __launch_bounds__(256) void k_init(
        int* __restrict__ cnt, int* __restrict__ fill, float* __restrict__ psum_rep,
        const float* __restrict__ W2, const float* __restrict__ W3,
        _Float16* __restrict__ Wt2, _Float16* __restrict__ Wt3) {
    int tid = blockIdx.x * blockDim.x + threadIdx.x;
    int nt = gridDim.x * blockDim.x;
    for (int i = tid; i < N_NODES; i += nt) { cnt[i] = 0; fill[i] = 0; }
    for (int i = tid; i < NREP * N_GRAPHS * HID; i += nt) psum_rep[i] = 0.f;
    for (int i = tid; i < 2 * HID * HID; i += nt) {
        int rem = i & (HID * HID - 1);
        int k = rem & 127, f = rem >> 7;
        if (i < HID * HID) Wt2[rem] = (_Float16)W2[k * HID + f];
        else               Wt3[rem] = (_Float16)W3[k * HID + f];
    }
}

// ---------- 2. degree count (edge atomics only; 50k addresses = low contention) ----------

__global__ __launch_bounds__(256) void k_count(
        const int* __restrict__ dst, int* __restrict__ cnt) {
    int e = blockIdx.x * blockDim.x + threadIdx.x;
    if (e < N_EDGES) atomicAdd(&cnt[dst[e]], 1);
}

// ---------- 3. per-chunk sums + dinv ----------

__global__ void k_chunksum(const int* __restrict__ cnt, int* __restrict__ csum,
                           float* __restrict__ dinv) {
    __shared__ int sh[256];
    int b = blockIdx.x, t = threadIdx.x;
    int i0 = b * CHUNK + t, i1 = i0 + 256;
    int v = 0;
    if (i0 < N_NODES) { int c = cnt[i0]; v += c; dinv[i0] = rsqrtf((float)c + 1.0f); }
    if (i1 < N_NODES) { int c = cnt[i1]; v += c; dinv[i1] = rsqrtf((float)c + 1.0f); }
    sh[t] = v; __syncthreads();
    for (int off = 128; off > 0; off >>= 1) {
        if (t < off) sh[t] += sh[t + off];
        __syncthreads();
    }
    if (t == 0) csum[b] = sh[0];
}

// ---------- 4. per-chunk exclusive scan -> row_start ----------

__global__ void k_scan(const int* __restrict__ cnt, const int* __restrict__ csum,
                       int* __restrict__ row_start) {
    __shared__ int ws[4];
    int b = blockIdx.x, t = threadIdx.x;
    int lane = t & 63, w = t >> 6;

    int pre = 0;
    for (int j = lane; j < b; j += 64) pre += csum[j];
    #pragma unroll
    for (int off = 32; off > 0; off >>= 1) pre += __shfl_down(pre, off);
    pre = __shfl(pre, 0);

    int base = b * CHUNK;
    int i0 = base + 2 * t, i1 = i0 + 1;
    int c0 = (i0 < N_NODES) ? cnt[i0] : 0;
    int c1 = (i1 < N_NODES) ? cnt[i1] : 0;
    int v = c0 + c1;
    int s = v;
    #pragma unroll
    for (int off = 1; off < 64; off <<= 1) {
        int u = __shfl_up(s, off);
        if (lane >= off) s += u;
    }
    if (lane == 63) ws[w] = s;
    __syncthreads();
    if (t == 0) {
        int r = 0;
        #pragma unroll
        for (int j = 0; j < 4; ++j) { int xx = ws[j]; ws[j] = r; r += xx; }
    }
    __syncthreads();
    int excl = s - v + ws[w] + pre;
    if (i0 < N_NODES) row_start[i0] = excl;
    if (i1 < N_NODES) row_start[i1] = excl + c0;
    if (b == 0 && t == 0) row_start[N_NODES] = N_EDGES;
}

// ---------- 5. scatter edges into CSR order ----------

__global__ __launch_bounds__(256) void k_scatter(
        const int* __restrict__ src, const int* __restrict__ dst,
        const float* __restrict__ dinv, const int* __restrict__ row_start,
        int* __restrict__ fill, int2* __restrict__ e_pack) {
    int e = blockIdx.x * blockDim.x + threadIdx.x;
    if (e >= N_EDGES) return;
    int d = dst[e];
    int pos = row_start[d] + atomicAdd(&fill[d], 1);
    int s = src[e];
    e_pack[pos] = make_int2(s, __float_as_int(dinv[s]));
}

// ---------- 6. fused layer 1: agg(x) + gemm1 + bn + relu -> H16 ----------

__global__ __launch_bounds__(256) void k_agg5g1(
        const float* __restrict__ x, const float* __restrict__ dinv,
        const int* __restrict__ row_start, const int2* __restrict__ e_pack,
        const float* __restrict__ W1, const float* __restrict__ b1,
        const float* __restrict__ g1, const float* __restrict__ be1,
        __half2* __restrict__ H16) {
    int gid = blockIdx.x * blockDim.x + threadIdx.x;
    int i = gid >> 3, k = gid & 7;
    if (i >= N_NODES) return;
    float acc = 0.f;
    if (k < IN_D) {
        int beg = row_start[i], end = row_start[i + 1];
        int e = beg;
        for (; e + 3 < end; e += 4) {
            int2 p0 = e_pack[e];
            int2 p1 = e_pack[e + 1];
            int2 p2 = e_pack[e + 2];
            int2 p3 = e_pack[e + 3];
            float x0 = x[p0.x * IN_D + k];
            float x1 = x[p1.x * IN_D + k];
            float x2 = x[p2.x * IN_D + k];
            float x3 = x[p3.x * IN_D + k];
            acc = fmaf(__int_as_float(p0.y), x0, acc);
            acc = fmaf(__int_as_float(p1.y), x1, acc);
            acc = fmaf(__int_as_float(p2.y), x2, acc);
            acc = fmaf(__int_as_float(p3.y), x3, acc);
        }
        for (; e < end; ++e) {
            int2 p = e_pack[e];
            acc = fmaf(__int_as_float(p.y), x[p.x * IN_D + k], acc);
        }
        float di = dinv[i];
        acc = di * (acc + di * x[i * IN_D + k]);
    }
    int lane = threadIdx.x & 63;
    int base = lane & ~7;
    float a0 = __shfl(acc, base + 0);
    float a1 = __shfl(acc, base + 1);
    float a2 = __shfl(acc, base + 2);
    float a3 = __shfl(acc, base + 3);
    float a4 = __shfl(acc, base + 4);
    const float rs = rsqrtf(1.0f + 1e-5f);
    int f0 = k * 16;
    #pragma unroll
    for (int u = 0; u < 8; ++u) {
        int fa = f0 + u * 2, fb = fa + 1;
        float va = b1[fa], vb = b1[fb];
        va = fmaf(a0, W1[0 * HID + fa], va); vb = fmaf(a0, W1[0 * HID + fb], vb);
        va = fmaf(a1, W1[1 * HID + fa], va); vb = fmaf(a1, W1[1 * HID + fb], vb);
        va = fmaf(a2, W1[2 * HID + fa], va); vb = fmaf(a2, W1[2 * HID + fb], vb);
        va = fmaf(a3, W1[3 * HID + fa], va); vb = fmaf(a3, W1[3 * HID + fb], vb);
        va = fmaf(a4, W1[4 * HID + fa], va); vb = fmaf(a4, W1[4 * HID + fb], vb);
        va = fmaf(va, g1[fa] * rs, be1[fa]);
        vb = fmaf(vb, g1[fb] * rs, be1[fb]);
        va = va > 0.f ? va : 0.f;
        vb = vb > 0.f ? vb : 0.f;
        H16[(size_t)i * 64 + k * 8 + u] = __floats2half2_rn(va, vb);
    }
}

// ---------- 7/9. aggregation over fp16 table -> fp16 A ----------

__global__ __launch_bounds__(256) void k_agg128h(
        const __half2* __restrict__ H2, const float* __restrict__ dinv,
        const int* __restrict__ row_start, const int2* __restrict__ e_pack,
        __half2* __restrict__ A16) {
    int n = (blockIdx.x * blockDim.x + threadIdx.x) >> 6;
    int lane = threadIdx.x & 63;
    if (n >= N_NODES) return;
    float2 acc = make_float2(0.f, 0.f);
    int beg = row_start[n], end = row_start[n + 1];
    int e = beg;
    for (; e + 7 < end; e += 8) {
        int2 p[8];
        float2 h[8];
        #pragma unroll
        for (int u = 0; u < 8; ++u) p[u] = e_pack[e + u];
        #pragma unroll
        for (int u = 0; u < 8; ++u)
            h[u] = __half22float2(H2[(size_t)p[u].x * 64 + lane]);
        #pragma unroll
        for (int u = 0; u < 8; ++u) {
            float w = __int_as_float(p[u].y);
            acc.x = fmaf(w, h[u].x, acc.x);
            acc.y = fmaf(w, h[u].y, acc.y);
        }
    }
    for (; e + 3 < end; e += 4) {
        int2 p[4];
        float2 h[4];
        #pragma unroll
        for (int u = 0; u < 4; ++u) p[u] = e_pack[e + u];
        #pragma unroll
        for (int u = 0; u < 4; ++u)
            h[u] = __half22float2(H2[(size_t)p[u].x * 64 + lane]);
        #pragma unroll
        for (int u = 0; u < 4; ++u) {
            float w = __int_as_float(p[u].y);
            acc.x = fmaf(w, h[u].x, acc.x);
            acc.y = fmaf(w, h[u].y, acc.y);
        }
    }
    for (; e < end; ++e) {
        int2 pe = e_pack[e];
        float w = __int_as_float(pe.y);
        float2 f = __half22float2(H2[(size_t)pe.x * 64 + lane]);
        acc.x = fmaf(w, f.x, acc.x);
        acc.y = fmaf(w, f.y, acc.y);
    }
    float di = dinv[n];
    float2 hs = __half22float2(H2[(size_t)n * 64 + lane]);
    acc.x = fmaf(di, hs.x, acc.x);
    acc.y = fmaf(di, hs.y, acc.y);
    A16[(size_t)n * 64 + lane] = __floats2half2_rn(di * acc.x, di * acc.y);
}

// ---------- 8. layer-2 MFMA gemm -> H16 (fp16) ----------
// A[m=lane&15][k=quad*8+j]; B via f-major Wt; C/D col=lane&15,row=quad*4+reg.

__global__ __launch_bounds__(256) void k_gemm2(
        const _Float16* __restrict__ A16, const _Float16* __restrict__ Wt,
        const float* __restrict__ bb, const float* __restrict__ gg,
        const float* __restrict__ bee, _Float16* __restrict__ outH) {
    int t = threadIdx.x;
    int w = t >> 6, lane = t & 63;
    int quad = lane >> 4, r16 = lane & 15;
    int nb = blockIdx.x * 64 + w * 16;
    const float rs = rsqrtf(1.0f + 1e-5f);
    const half8* Arow = (const half8*)(A16 + (size_t)(nb + r16) * 128);
    half8 a[4];
    #pragma unroll
    for (int kb = 0; kb < 4; ++kb) a[kb] = Arow[kb * 4 + quad];
    #pragma unroll
    for (int ft = 0; ft < 8; ++ft) {
        int f = ft * 16 + r16;
        const half8* Brow = (const half8*)(Wt + (size_t)f * 128);
        float4v acc = {0.f, 0.f, 0.f, 0.f};
        #pragma unroll
        for (int kb = 0; kb < 4; ++kb)
            acc = __builtin_amdgcn_mfma_f32_16x16x32_f16(a[kb], Brow[kb * 4 + quad],
                                                         acc, 0, 0, 0);
        float b0 = bb[f], g0 = gg[f] * rs, e0 = bee[f];
        #pragma unroll
        for (int rr = 0; rr < 4; ++rr) {
            int n = nb + quad * 4 + rr;
            if (n < N_NODES) {
                float v = fmaf(acc[rr] + b0, g0, e0);
                v = v > 0.f ? v : 0.f;
                outH[(size_t)n * 128 + f] = (_Float16)v;
            }
        }
    }
}

// ---------- 10. layer-3 MFMA gemm + fused mean-pool ----------
// LDS-local accumulation (block's 64 sorted nodes span <=NLOC graphs) then one
// replicated global atomic per (graph,f) present -> ~1 hit/address (R8 lesson:
// 400k atomics on 8192 addresses = 45us of cross-XCD serialization).

__global__ __launch_bounds__(256) void k_gemm3pool(
        const _Float16* __restrict__ A16, const _Float16* __restrict__ Wt,
        const float* __restrict__ bb, const float* __restrict__ gg,
        const float* __restrict__ bee, const int* __restrict__ batch,
        float* __restrict__ psum_rep) {
    __shared__ float sh_pool[NLOC][HID];
    int t = threadIdx.x;
    int w = t >> 6, lane = t & 63;
    int quad = lane >> 4, r16 = lane & 15;
    int blk = (int)blockIdx.x;
    int nb = blk * 64 + w * 16;
    const float rs = rsqrtf(1.0f + 1e-5f);

    for (int i = t; i < NLOC * HID; i += 256) ((float*)sh_pool)[i] = 0.f;

    const half8* Arow = (const half8*)(A16 + (size_t)(nb + r16) * 128);
    half8 a[4];
    #pragma unroll
    for (int kb = 0; kb < 4; ++kb) a[kb] = Arow[kb * 4 + quad];

    int nb0 = blk * 64;
    if (nb0 > N_NODES - 1) nb0 = N_NODES - 1;
    int g0 = batch[nb0];   // first graph id in this 64-node tile
    int gi4[4];
    #pragma unroll
    for (int rr = 0; rr < 4; ++rr) {
        int n = nb + quad * 4 + rr;
        gi4[rr] = (n < N_NODES) ? batch[n] : -1;
    }
    __syncthreads();

    float* rep = psum_rep + (size_t)(blk & (NREP - 1)) * N_GRAPHS * HID;

    #pragma unroll
    for (int ft = 0; ft < 8; ++ft) {
        int f = ft * 16 + r16;
        const half8* Brow = (const half8*)(Wt + (size_t)f * 128);
        float4v acc = {0.f, 0.f, 0.f, 0.f};
        #pragma unroll
        for (int kb = 0; kb < 4; ++kb)
            acc = __builtin_amdgcn_mfma_f32_16x16x32_f16(a[kb], Brow[kb * 4 + quad],
                                                         acc, 0, 0, 0);
        float b0 = bb[f], g0f = gg[f] * rs, e0 = bee[f];
        float partial = 0.f;
        int cur = -1;
        #pragma unroll
        for (int rr = 0; rr < 4; ++rr) {
            int gi = gi4[rr];
            if (gi >= 0) {
                float v = fmaf(acc[rr] + b0, g0f, e0);
                v = v > 0.f ? v : 0.f;
                if (gi != cur) {
                    if (cur >= 0) {
                        int idx = cur - g0;
                        if (idx < NLOC) atomicAdd(&sh_pool[idx][f], partial);
                        else            atomicAdd(&rep[cur * HID + f], partial);
                    }
                    partial = 0.f; cur = gi;
                }
                partial += v;
            }
        }
        if (cur >= 0) {
            int idx = cur - g0;
            if (idx < NLOC) atomicAdd(&sh_pool[idx][f], partial);
            else            atomicAdd(&rep[cur * HID + f], partial);
        }
    }
    __syncthreads();
    // flush LDS partials: one replicated global atomic per (graph,f) present
    for (int i = t; i < NLOC * HID; i += 256) {
        int idx = i >> 7, f = i & 127;
        float v = sh_pool[idx][f];
        int g = g0 + idx;
        if (v != 0.f && g < N_GRAPHS) atomicAdd(&rep[g * HID + f], v);
    }
}

// ---------- 11. projection (+ graph counts via binary search, no atomics) ----------

__device__ __forceinline__ int lower_bound_batch(const int* __restrict__ batch, int val) {
    int lo = 0, hi = N_NODES;
    while (lo < hi) {
        int mid = (lo + hi) >> 1;
        if (batch[mid] < val) lo = mid + 1;
        else hi = mid;
    }
    return lo;
}

__global__ void k_final(const float* __restrict__ psum_rep, const int* __restrict__ batch,
                        const float* __restrict__ Wp, const float* __restrict__ bp,
                        float* __restrict__ out) {
    __shared__ float s_p[HID];
    int gi = blockIdx.x, e = threadIdx.x;   // 64 threads
    // sum the NREP replicas cooperatively
    for (int f = e; f < HID; f += EMB) {
        float v = 0.f;
        #pragma unroll
        for (int r = 0; r < NREP; ++r)
            v += psum_rep[(size_t)r * N_GRAPHS * HID + gi * HID + f];
        s_p[f] = v;
    }
    int lane = e & 63;
    int r = 0;
    if (lane < 2) r = lower_bound_batch(batch, gi + lane);
    int c0 = __shfl(r, 0), c1 = __shfl(r, 1);
    float inv = 1.0f / fmaxf((float)(c1 - c0), 1.0f);
    __syncthreads();
    float acc = bp[e];
    #pragma unroll 8
    for (int f = 0; f < HID; ++f)
        acc = fmaf(s_p[f] * inv, Wp[f * EMB + e], acc);
    out[gi * EMB + e] = acc;
}

// ---------- launcher ----------

extern "C" void kernel_launch(void* const* d_in, const int* in_sizes, int n_in,
                              void* d_out, int out_size, void* d_ws, size_t ws_size,
                              hipStream_t stream) {
    const float* x   = (const float*)d_in[0];
    const int*   src = (const int*)d_in[1];
    const int*   dst = (const int*)d_in[2];
    const int* batch = (const int*)d_in[3];
    const float* W1 = (const float*)d_in[4];
    const float* b1 = (const float*)d_in[5];
    const float* W2 = (const float*)d_in[6];
    const float* b2 = (const float*)d_in[7];
    const float* W3 = (const float*)d_in[8];
    const float* b3 = (const float*)d_in[9];
    const float* g1 = (const float*)d_in[10];
    const float* be1 = (const float*)d_in[11];
    const float* g2 = (const float*)d_in[12];
    const float* be2 = (const float*)d_in[13];
    const float* g3 = (const float*)d_in[14];
    const float* be3 = (const float*)d_in[15];
    const float* Wp = (const float*)d_in[16];
    const float* bp = (const float*)d_in[17];
    float* out = (float*)d_out;

    char* ws = (char*)d_ws;
    size_t o = 0;
    auto alloc = [&](size_t bytes) {
        void* pp = ws + o;
        o += bytes;
        o = (o + 255) & ~255ull;
        return pp;
    };
    int*      cnt       = (int*)alloc(N_NODES * 4);
    int*      fill      = (int*)alloc(N_NODES * 4);
    int*      row_start = (int*)alloc((N_NODES + 1) * 4);
    int*      csum      = (int*)alloc(NCHUNK * 4);
    float*    dinv      = (float*)alloc(N_NODES * 4);
    int2*     e_pack    = (int2*)alloc((size_t)N_EDGES * 8);
    _Float16* Wt2       = (_Float16*)alloc(HID * HID * 2);
    _Float16* Wt3       = (_Float16*)alloc(HID * HID * 2);
    __half2*  H16       = (__half2*)alloc((size_t)(N_NODES + 64) * HID * 2);
    __half2*  A16       = (__half2*)alloc((size_t)(N_NODES + 64) * HID * 2);
    float*    psum_rep  = (float*)alloc((size_t)NREP * N_GRAPHS * HID * 4);

    k_init<<<512, 256, 0, stream>>>(cnt, fill, psum_rep, W2, W3, Wt2, Wt3);
    k_count<<<(N_EDGES + 255) / 256, 256, 0, stream>>>(dst, cnt);
    k_chunksum<<<NCHUNK, 256, 0, stream>>>(cnt, csum, dinv);
    k_scan<<<NCHUNK, 256, 0, stream>>>(cnt, csum, row_start);
    k_scatter<<<(N_EDGES + 255) / 256, 256, 0, stream>>>(src, dst, dinv, row_start,
                                                         fill, e_pack);
    k_agg5g1<<<(N_NODES * 8 + 255) / 256, 256, 0, stream>>>(x, dinv, row_start, e_pack,
                                                            W1, b1, g1, be1, H16);
    k_agg128h<<<(N_NODES * 64 + 255) / 256, 256, 0, stream>>>(H16, dinv, row_start,
                                                              e_pack, A16);
    k_gemm2<<<(N_NODES + 63) / 64, 256, 0, stream>>>((const _Float16*)A16, Wt2,
                                                     b2, g2, be2, (_Float16*)H16);
    k_agg128h<<<(N_NODES * 64 + 255) / 256, 256, 0, stream>>>(H16, dinv, row_start,
                                                              e_pack, A16);
    k_gemm3pool<<<(N_NODES + 63) / 64, 256, 0, stream>>>((const _Float16*)A16, Wt3,
                                                         b3, g3, be3, batch, psum_rep);
    k_final<<<N_GRAPHS, EMB, 0, stream>>>(psum_rep, batch, Wp, bp, out);
}